// Round 1
// 1420.387 us; speedup vs baseline: 1.0715x; 1.0715x over previous
//
#include <hip/hip_runtime.h>

#define TT 512
#define VV 64
#define RING 16   // was 8: ring depth doubled so producer lead (~9) sits well under the gate (13)

typedef _Float16 f16;
typedef f16 f16x8 __attribute__((ext_vector_type(8)));
typedef f16 f16x4 __attribute__((ext_vector_type(4)));
typedef float f32x4v __attribute__((ext_vector_type(4)));
typedef unsigned long long u64;
typedef unsigned u32;

#define MFMA(A_,B_,C_) __builtin_amdgcn_mfma_f32_16x16x32_f16((A_),(B_),(C_),0,0,0)
#define AT_LD32(p)   __hip_atomic_load((p), __ATOMIC_RELAXED, __HIP_MEMORY_SCOPE_AGENT)
#define AT_ST32(p,v) __hip_atomic_store((p),(v), __ATOMIC_RELAXED, __HIP_MEMORY_SCOPE_AGENT)
#define AT_LD64(p)   __hip_atomic_load((p), __ATOMIC_RELAXED, __HIP_MEMORY_SCOPE_AGENT)
#define AT_ST64(p,v) __hip_atomic_store((p),(v), __ATOMIC_RELAXED, __HIP_MEMORY_SCOPE_AGENT)

__device__ __forceinline__ void barrier_lds(){ asm volatile("s_waitcnt lgkmcnt(0)\n\ts_barrier" ::: "memory"); }
__device__ __forceinline__ void wait_vm0(){ asm volatile("s_waitcnt vmcnt(0)" ::: "memory"); }
__device__ __forceinline__ float4 ld4(const float* p){ return *(const float4*)p; }

__device__ __forceinline__ f16x8 ldA8(const float* p){
  f16x8 a;
  #pragma unroll
  for (int j = 0; j < 8; ++j) a[j] = (f16)p[j];
  return a;
}

// element offset (in f16 units) of (k=d0..d0+3, col=b) inside a B-frag buffer
// layout: [kt][lane'][j], lane' = ((d&31)>>3)*16 + b, j = d&7
__device__ __forceinline__ int fragOff16(int d0, int b){
  const int kt = d0 >> 5, qq = (d0 >> 3) & 3, j0 = d0 & 7;
  return (kt*64 + qq*16 + b)*8 + j0;
}

__device__ __forceinline__ void fragW_lds(f16x8* buf, int d0, int b, const float* h4){
  f16x4 v;
  #pragma unroll
  for (int e = 0; e < 4; ++e) v[e] = (f16)h4[e];
  *(f16x4*)((f16*)buf + fragOff16(d0, b)) = v;
}

__device__ __forceinline__ void pubFrag(char* slot, int d0, int b, const float* h4){
  union { f16x4 v; u64 u; } uu;
  #pragma unroll
  for (int e = 0; e < 4; ++e) uu.v[e] = (f16)h4[e];
  AT_ST64((u64*)(slot + fragOff16(d0, b)*2), uu.u);
}

__device__ __forceinline__ f16x8 impFrag(const char* slot, int kt, int lane){
  union { u64 u[2]; f16x8 v; } vv;
  const u64* p = (const u64*)(slot + (kt*64 + lane)*16);
  vv.u[0] = AT_LD64((u64*)p);
  vv.u[1] = AT_LD64((u64*)(p + 1));
  return vv.v;
}

__device__ __forceinline__ void spin_ge(u32* f, u32 val){
  if ((threadIdx.x & 63) == 0){
    u32 g = 0;
    while (AT_LD32(f) < val && ++g < (1u << 20)) {}
  }
  asm volatile("" ::: "memory");
}

__device__ __forceinline__ void gates_upd(const f32x4v* Ci, const f32x4v* Ch,
                                          const float* bR, const float* bZ,
                                          const float* bI, const float* bH,
                                          float* hp){
  #pragma unroll
  for (int e = 0; e < 4; ++e){
    float rr = 1.f/(1.f + __expf(-(Ci[0][e] + Ch[0][e] + bR[e])));
    float zz = 1.f/(1.f + __expf(-(Ci[1][e] + Ch[1][e] + bZ[e])));
    float nv = Ci[2][e] + bI[e] + rr*(Ch[2][e] + bH[e]);
    float nn = 1.f - 2.f/(1.f + __expf(2.f*nv));
    hp[e] = (1.f - zz)*nn + zz*hp[e];
  }
}

__global__ void k_init(u32* wsf){
  const int i = blockIdx.x*256 + threadIdx.x;
  if (i < 4096) AT_ST32(wsf + i, 0u);
}

// roles: 0=L1 (x-path -> ch0), 1=L2 (ch0->ch1), 2=L3+head (ch1 -> y)
// Protocol (per channel): producer publishes slot t&15; flag FLP=t+1 every 4 steps
// (after vm0 drain). Consumer prefetches slot t+1 at START of step t (validity:
// slots <= FLP-1; spin target min(t+7,TT) grants lead ~9). Producer overwrite gate:
// ACK >= t-13 (first alias needs lead 17 on a 16-ring -> 4-slot margin).
__launch_bounds__(256, 1)
__global__ void k_pipe(const float* __restrict__ x,   const float* __restrict__ dd,
                       const float* __restrict__ m1,
                       const float* __restrict__ h01, const float* __restrict__ h02,
                       const float* __restrict__ h03,
                       const float* __restrict__ Wih1, const float* __restrict__ Whh1,
                       const float* __restrict__ bih1, const float* __restrict__ bhh1,
                       const float* __restrict__ Wih2, const float* __restrict__ Whh2,
                       const float* __restrict__ bih2, const float* __restrict__ bhh2,
                       const float* __restrict__ Wih3, const float* __restrict__ Whh3,
                       const float* __restrict__ bih3, const float* __restrict__ bhh3,
                       const float* __restrict__ Wout, const float* __restrict__ bout,
                       const float* __restrict__ Wdx,  const float* __restrict__ bdx,
                       const float* __restrict__ Wdh,  const float* __restrict__ bdh,
                       float* __restrict__ y, u32* __restrict__ wsf, char* __restrict__ wsd)
{
  __shared__ f16x8 sFrag[2][256];
  __shared__ f16x8 sX1[2][128];
  __shared__ f16x8 sHead[2][256];

  const int tid = threadIdx.x, w = tid >> 6, lane = tid & 63;
  const int q = lane >> 4, r = lane & 15;
  const int blk = blockIdx.x, role = blk >> 5, grp = blk & 31, b0 = grp << 4;

  u32* const FL  = wsf;
  u32* const ACK = wsf + 1024;

#define SLOT(ch,s) (wsd + (size_t)((((ch)*32 + grp)*RING + (s)))*4096)
#define FLP(ch)    (FL  + ((ch)*32 + grp)*16)
#define ACKP(ch)   (ACK + ((ch)*32 + grp)*16)

  // ---- per-thread hidden-dim biases (all roles L1..L3) ----
  const float* bihX = (role == 0) ? bih1 : (role == 1) ? bih2 : bih3;
  const float* bhhX = (role == 0) ? bhh1 : (role == 1) ? bhh2 : bhh3;
  const float* h0X  = (role == 0) ? h01  : (role == 1) ? h02  : h03;

  float bR[2][4], bZ[2][4], bI[2][4], bH[2][4];
  float hS[2][4], WdhL[2][4], bdhL[2][4];
  #pragma unroll
  for (int G = 0; G < 2; ++G){
    const int dG = (w + 4*G)*16 + 4*q;
    #pragma unroll
    for (int e = 0; e < 4; ++e){
      const int d = dG + e;
      bR[G][e] = bihX[d] + bhhX[d];
      bZ[G][e] = bihX[128+d] + bhhX[128+d];
      bI[G][e] = bihX[256+d];
      bH[G][e] = bhhX[256+d];
      WdhL[G][e] = Wdh[d]; bdhL[G][e] = bdh[d];
    }
    float4 a = ld4(h0X + (size_t)(b0+r)*128 + dG);
    hS[G][0]=a.x; hS[G][1]=a.y; hS[G][2]=a.z; hS[G][3]=a.w;
  }
  float dhC = 0.f, dhN = dd[(size_t)(b0+r)*TT + 1];

  // ===================== L1 =====================
  if (role == 0){
    f16x8 Ai[2][3][2], Ah[2][3][4];
    #pragma unroll
    for (int G = 0; G < 2; ++G){
      #pragma unroll
      for (int g = 0; g < 3; ++g){
        const int mrow = (g*8 + w + 4*G)*16 + r;
        #pragma unroll
        for (int kt = 0; kt < 2; ++kt) Ai[G][g][kt] = ldA8(Wih1 + mrow*64 + kt*32 + q*8);
        #pragma unroll
        for (int kt = 0; kt < 4; ++kt) Ah[G][g][kt] = ldA8(Whh1 + mrow*128 + kt*32 + q*8);
      }
    }
    const int bx = w*4 + q, v0 = 4*r;
    float Wdx4[4], bdx4[4];
    #pragma unroll
    for (int e = 0; e < 4; ++e){ Wdx4[e] = Wdx[v0+e]; bdx4[e] = bdx[v0+e]; }

    float4 xC = ld4(x + ((size_t)(b0+bx)*TT + 0)*VV + v0);
    const float4 x0v = xC;
    float4 xN = ld4(x  + ((size_t)(b0+bx)*TT + 1)*VV + v0);
    float4 mN = ld4(m1 + ((size_t)(b0+bx)*TT + 1)*VV + v0);
    float dxN = dd[(size_t)(b0+bx)*TT + 1];
    float4 xP = xC, mC = mN; float dxC = dxN;
    __syncthreads();

    for (int t = 0; t < TT; ++t){
      const int par = t & 1;
      if ((t & 3) == 0 && t >= 16) spin_ge(ACKP(0), (u32)(t-13));
      float xi[4];
      if (t == 0){ xi[0]=xC.x; xi[1]=xC.y; xi[2]=xC.z; xi[3]=xC.w; }
      else {
        const float* xc = (const float*)&xC; const float* xp = (const float*)&xP;
        const float* x0e = (const float*)&x0v; const float* me = (const float*)&mC;
        #pragma unroll
        for (int e = 0; e < 4; ++e){
          float gx = __expf(-fmaxf(dxC*Wdx4[e] + bdx4[e], 0.f));
          xi[e] = (xp[e]*gx + (1.f-gx)*x0e[e])*(1.f-me[e]) + me[e]*xc[e];
        }
      }
      fragW_lds(&sX1[par][0], v0, bx, xi);
      #pragma unroll
      for (int G = 0; G < 2; ++G){
        const int dG = (w + 4*G)*16 + 4*q;
        if (t >= 1){
          #pragma unroll
          for (int e = 0; e < 4; ++e)
            hS[G][e] *= __expf(-fmaxf(dhC*WdhL[G][e] + bdhL[G][e], 0.f));
        }
        fragW_lds(&sFrag[par][0], dG, r, hS[G]);
      }
      barrier_lds();
      f16x8 bx1[2], bh4[4];
      #pragma unroll
      for (int kt = 0; kt < 2; ++kt) bx1[kt] = sX1[par][kt*64 + lane];
      #pragma unroll
      for (int kt = 0; kt < 4; ++kt) bh4[kt] = sFrag[par][kt*64 + lane];
      f32x4v Ci[2][3], Ch[2][3];
      #pragma unroll
      for (int G = 0; G < 2; ++G)
        #pragma unroll
        for (int g = 0; g < 3; ++g){ Ci[G][g] = (f32x4v){0,0,0,0}; Ch[G][g] = (f32x4v){0,0,0,0}; }
      #pragma unroll
      for (int G = 0; G < 2; ++G)
        #pragma unroll
        for (int g = 0; g < 3; ++g){
          #pragma unroll
          for (int kt = 0; kt < 4; ++kt) Ch[G][g] = MFMA(Ah[G][g][kt], bh4[kt], Ch[G][g]);
          #pragma unroll
          for (int kt = 0; kt < 2; ++kt) Ci[G][g] = MFMA(Ai[G][g][kt], bx1[kt], Ci[G][g]);
        }
      char* sOut = SLOT(0, t & (RING-1));
      #pragma unroll
      for (int G = 0; G < 2; ++G){
        const int dG = (w + 4*G)*16 + 4*q;
        gates_upd(&Ci[G][0], &Ch[G][0], bR[G], bZ[G], bI[G], bH[G], hS[G]);
        pubFrag(sOut, dG, r, hS[G]);
      }
      if ((t & 3) == 3){
        wait_vm0();
        barrier_lds();
        if (tid == 0) AT_ST32(FLP(0), (u32)(t+1));
      }
      xP = xC; xC = xN; mC = mN; dhC = dhN; dxC = dxN;
      const int tp = (t+2 < TT) ? (t+2) : (TT-1);
      xN  = ld4(x  + ((size_t)(b0+bx)*TT + tp)*VV + v0);
      mN  = ld4(m1 + ((size_t)(b0+bx)*TT + tp)*VV + v0);
      dhN = dd[(size_t)(b0+r)*TT + tp];
      dxN = dd[(size_t)(b0+bx)*TT + tp];
    }
    return;
  }

  // ===================== L2 / L3+head =====================
  {
    const float* Wihp = (role == 1) ? Wih2 : Wih3;
    const float* Whhp = (role == 1) ? Whh2 : Whh3;
    const int cIn = role - 1;

    f16x8 Ai[2][3][4], Ah[2][3][4];
    #pragma unroll
    for (int G = 0; G < 2; ++G){
      #pragma unroll
      for (int g = 0; g < 3; ++g){
        const int mrow = (g*8 + w + 4*G)*16 + r;
        #pragma unroll
        for (int kt = 0; kt < 4; ++kt){
          Ai[G][g][kt] = ldA8(Wihp + mrow*128 + kt*32 + q*8);
          Ah[G][g][kt] = ldA8(Whhp + mrow*128 + kt*32 + q*8);
        }
      }
    }
    // head weights (role 2 only; all waves compute, wave0 stores)
    f16x8 aO[4]; float bo4[4];
    if (role == 2){
      #pragma unroll
      for (int kt = 0; kt < 4; ++kt){
        f16x8 a;
        #pragma unroll
        for (int j = 0; j < 8; ++j)
          a[j] = (r < 4) ? (f16)Wout[r*128 + kt*32 + q*8 + j] : (f16)0.f;
        aO[kt] = a;
      }
      #pragma unroll
      for (int e = 0; e < 4; ++e) bo4[e] = bout[e];
    }
    __syncthreads();

    // preload: wait for first 8 steps (covers prefetch of slots 1..7 in window 0),
    // import step 0
    spin_ge(FLP(cIn), 8u);
    f16x8 bi[4], biN[4];
    #pragma unroll
    for (int kt = 0; kt < 4; ++kt) bi[kt] = impFrag(SLOT(cIn, 0), kt, lane);

    for (int t = 0; t < TT; ++t){
      const int par = t & 1;
      if (role == 1 && (t & 3) == 0 && t >= 16) spin_ge(ACKP(1), (u32)(t-13));
      // prefetch NEXT step's input frags at START of step t: a full step (~1 us)
      // of compute covers the L3-class import latency. Validity: slots <= FLP-1,
      // and the window spins (target t+7) keep slot t+1 always granted.
      if (t + 1 < TT){
        const char* sIn = SLOT(cIn, (t+1) & (RING-1));
        #pragma unroll
        for (int kt = 0; kt < 4; ++kt) biN[kt] = impFrag(sIn, kt, lane);
      }
      #pragma unroll
      for (int G = 0; G < 2; ++G){
        const int dG = (w + 4*G)*16 + 4*q;
        if (t >= 1){
          #pragma unroll
          for (int e = 0; e < 4; ++e)
            hS[G][e] *= __expf(-fmaxf(dhC*WdhL[G][e] + bdhL[G][e], 0.f));
        }
        fragW_lds(&sFrag[par][0], dG, r, hS[G]);
      }
      barrier_lds();
      if (role == 1 && tid == 0) AT_ST32(ACKP(0), (u32)t);   // steps <= t-1 fully consumed
      f16x8 bh4[4];
      #pragma unroll
      for (int kt = 0; kt < 4; ++kt) bh4[kt] = sFrag[par][kt*64 + lane];
      f32x4v Ci[2][3], Ch[2][3];
      #pragma unroll
      for (int G = 0; G < 2; ++G)
        #pragma unroll
        for (int g = 0; g < 3; ++g){ Ci[G][g] = (f32x4v){0,0,0,0}; Ch[G][g] = (f32x4v){0,0,0,0}; }
      #pragma unroll
      for (int G = 0; G < 2; ++G)
        #pragma unroll
        for (int g = 0; g < 3; ++g){
          #pragma unroll
          for (int kt = 0; kt < 4; ++kt) Ch[G][g] = MFMA(Ah[G][g][kt], bh4[kt], Ch[G][g]);
          #pragma unroll
          for (int kt = 0; kt < 4; ++kt) Ci[G][g] = MFMA(Ai[G][g][kt], bi[kt], Ci[G][g]);
        }
      #pragma unroll
      for (int G = 0; G < 2; ++G)
        gates_upd(&Ci[G][0], &Ch[G][0], bR[G], bZ[G], bI[G], bH[G], hS[G]);

      if (role == 1){
        char* sOut = SLOT(1, t & (RING-1));
        #pragma unroll
        for (int G = 0; G < 2; ++G){
          const int dG = (w + 4*G)*16 + 4*q;
          pubFrag(sOut, dG, r, hS[G]);
        }
        if ((t & 3) == 3){
          wait_vm0();
          barrier_lds();
          if (tid == 0) AT_ST32(FLP(1), (u32)(t+1));
          if (t < TT-1) spin_ge(FLP(0), (u32)(t+7 <= TT ? t+7 : TT));
        }
      } else {
        // head: write fresh h3 frags, barrier, MFMA + softmax, store y[., t, .]
        #pragma unroll
        for (int G = 0; G < 2; ++G){
          const int dG = (w + 4*G)*16 + 4*q;
          fragW_lds(&sHead[par][0], dG, r, hS[G]);
        }
        barrier_lds();
        if (tid == 0) AT_ST32(ACKP(1), (u32)(t+1));   // step t consumed
        f32x4v cl = {0.f,0.f,0.f,0.f};
        #pragma unroll
        for (int kt = 0; kt < 4; ++kt) cl = MFMA(aO[kt], sHead[par][kt*64 + lane], cl);
        if (tid < 16){
          float l0 = cl[0]+bo4[0], l1 = cl[1]+bo4[1], l2 = cl[2]+bo4[2], l3 = cl[3]+bo4[3];
          float mx = fmaxf(fmaxf(l0,l1), fmaxf(l2,l3));
          float e0 = __expf(l0-mx), e1 = __expf(l1-mx), e2 = __expf(l2-mx), e3 = __expf(l3-mx);
          float inv = 1.f/(e0+e1+e2+e3);
          float4 o; o.x = e0*inv; o.y = e1*inv; o.z = e2*inv; o.w = e3*inv;
          *(float4*)(y + ((size_t)(b0+tid)*TT + t)*4) = o;
        }
        if ((t & 3) == 3 && t < TT-1) spin_ge(FLP(1), (u32)(t+7 <= TT ? t+7 : TT));
      }

      // rotate prefetch buffer into place (compiler inserts the vmcnt wait here;
      // the import has had the whole step to complete)
      if (t + 1 < TT){
        #pragma unroll
        for (int kt = 0; kt < 4; ++kt) bi[kt] = biN[kt];
      }
      dhC = dhN;
      const int tp = (t+2 < TT) ? (t+2) : (TT-1);
      dhN = dd[(size_t)(b0+r)*TT + tp];
    }
  }
}

extern "C" void kernel_launch(void* const* d_in, const int* in_sizes, int n_in,
                              void* d_out, int out_size, void* d_ws, size_t ws_size,
                              hipStream_t stream) {
  (void)in_sizes; (void)n_in; (void)out_size; (void)ws_size;
  u32*  wsf = (u32*)d_ws;
  char* wsd = (char*)d_ws + 16384;
  k_init<<<dim3(16), dim3(256), 0, stream>>>(wsf);
  k_pipe<<<dim3(96), dim3(256), 0, stream>>>(
      (const float*)d_in[0],  (const float*)d_in[1],  (const float*)d_in[2],
      (const float*)d_in[3],  (const float*)d_in[4],  (const float*)d_in[5],
      (const float*)d_in[6],  (const float*)d_in[7],  (const float*)d_in[8],  (const float*)d_in[9],
      (const float*)d_in[10], (const float*)d_in[11], (const float*)d_in[12], (const float*)d_in[13],
      (const float*)d_in[14], (const float*)d_in[15], (const float*)d_in[16], (const float*)d_in[17],
      (const float*)d_in[18], (const float*)d_in[19],
      (const float*)d_in[20], (const float*)d_in[21],
      (const float*)d_in[22], (const float*)d_in[23],
      (float*)d_out, wsf, wsd);
}